// Round 6
// baseline (247.486 us; speedup 1.0000x reference)
//
#include <hip/hip_runtime.h>

#define NN 64
#define HH 512
#define MAGICF 0x7e57c0deu

typedef _Float16 h8 __attribute__((ext_vector_type(8)));
typedef _Float16 h4 __attribute__((ext_vector_type(4)));
typedef float    fx4 __attribute__((ext_vector_type(4)));

#define MFMA __builtin_amdgcn_mfma_f32_16x16x32_f16

// ---------------------------------------------------------------------------
// ws layout (bytes):
//   [0,        4 MiB)  W1f : per node, frag-ordered fp16 [8 c][2 ks][4 nt][64 lane][8]
//   [4 MiB,    8 MiB)  W2f : same shape
//   [8 MiB,   12 MiB)  W3f : same shape (cols 0..63 of W3)
//   [12 MiB, +128 KiB) w3c : per node, [512] fp32 = W3n[h][64+n]
//   [+128 KiB, +4 KiB) flags : [64 nodes][16 tiles] u32 (MAGICF when slice ready)
// total = 12,718,080 B
// For mfma_f32_16x16x32_f16 the A-frag and B-frag lane layouts are identical,
// so the same frag data serves swapped-operand MFMAs unchanged.
// ---------------------------------------------------------------------------
#define WS_NEEDED 12718080ull

typedef __attribute__((address_space(1))) const unsigned int gu32;
typedef __attribute__((address_space(3))) unsigned int       lu32;

__device__ __forceinline__ void gld16(const void* g, void* l) {
    // DMA 16B/lane global->LDS; LDS dest = wave-uniform base + lane*16
    __builtin_amdgcn_global_load_lds((gu32*)g, (lu32*)l, 16, 0, 0);
}

__device__ __forceinline__ h8 cvt8(const float* __restrict__ s) {
    float4 a = *(const float4*)s, b = *(const float4*)(s + 4);
    h8 h;
    h[0]=(_Float16)a.x; h[1]=(_Float16)a.y; h[2]=(_Float16)a.z; h[3]=(_Float16)a.w;
    h[4]=(_Float16)b.x; h[5]=(_Float16)b.y; h[6]=(_Float16)b.z; h[7]=(_Float16)b.w;
    return h;
}

// Convert slice s (256 frag-blocks) of node n's weights into ws. Idempotent:
// identical values regardless of which WG executes it (race-safe repair).
__device__ __forceinline__ void cvt_slice(int n, int s, int tid,
        const float* __restrict__ W1, const float* __restrict__ W2,
        const float* __restrict__ W3, char* __restrict__ ws)
{
    const int idx  = s * 256 + tid;              // 0..4095 within node
    const int c    = idx >> 9;
    const int ks   = (idx >> 8) & 1;
    const int nt   = (idx >> 6) & 3;
    const int l    = idx & 63;
    const int pos  = l & 15;
    const int quad = l >> 4;

    _Float16* o1 = (_Float16*)ws;
    _Float16* o2 = o1 + 2097152;
    _Float16* o3 = o2 + 2097152;
    float*    oc = (float*)(ws + 12582912);
    const size_t g = (size_t)n * 4096 + idx;

    // W1 frag: W1[n][c*64+nt*16+pos][ks*32+quad*8+j]
    *(h8*)(o1 + g * 8) = cvt8(W1 + (size_t)n * 32768
                                 + (size_t)(c * 64 + nt * 16 + pos) * 64
                                 + ks * 32 + quad * 8);
    // W2 frag: W2[n][nt*16+pos][c*64+ks*32+quad*8+j]
    *(h8*)(o2 + g * 8) = cvt8(W2 + (size_t)n * 32768
                                 + (size_t)(nt * 16 + pos) * 512
                                 + c * 64 + ks * 32 + quad * 8);
    // W3 frag (cols<64): W3[n][c*64+nt*16+pos][ks*32+quad*8+j]
    *(h8*)(o3 + g * 8) = cvt8(W3 + (size_t)n * 65536
                                 + (size_t)(c * 64 + nt * 16 + pos) * 128
                                 + ks * 32 + quad * 8);
    // w3c slice: oc[n][s*32+i] = W3[n][s*32+i][64+n]
    if (tid < 32)
        oc[n * 512 + s * 32 + tid] =
            W3[(size_t)n * 65536 + (size_t)(s * 32 + tid) * 128 + 64 + n];
}

// ---------------------------------------------------------------------------
// Fused kernel: 1024 WGs x 256 thr, 4 blocks/CU (guaranteed by launch_bounds +
// 32KB LDS -> all WGs co-resident). WG = (node n = bid&63, tile = bid>>6 of 64
// batch rows). Phase 0: convert own 1/16 weight slice (home-XCD L2 dirty).
// Node-group sync: 16 flags, acquire/release agent scope; bounded spin with
// idempotent self-repair on timeout (deadlock-impossible). Phase 1: mfma7
// pipeline (W1/W3 gld_lds dbuf, W2 reg-loaded, swapped MFMAs, packed b64
// transposes) with fold-MFMAs replaced by fp32 VALU FMAs.
// ---------------------------------------------------------------------------
__global__ __launch_bounds__(256, 4)
void causal_fused2(const float* __restrict__ x,  const float* __restrict__ W1,
                   const float* __restrict__ W2, const float* __restrict__ W3,
                   const float* __restrict__ b3, const float* __restrict__ W4,
                   const float* __restrict__ b4, char* __restrict__ ws,
                   float* __restrict__ out)
{
    __shared__ __align__(16) char smem[32000];
    _Float16* w1b  = (_Float16*)smem;            // [2][4096] halves (W1 dbuf; C reuses for W3)
    _Float16* priv = w1b + 8192;                 // [4 waves][16][72] halves
    float*    w3cs = (float*)(smem + 25600);     // [512] fp32
    float*    b3s  = (float*)(smem + 27648);     // [512] fp32
    float*    w4s  = (float*)(smem + 29696);     // [512] fp32
    float*    xns  = (float*)(smem + 31744);     // [64]  fp32
    __shared__ unsigned missLds;

    const int tid  = threadIdx.x;
    const int bid  = blockIdx.x;
    const int n    = bid & 63;                   // all of node n's WGs on XCD n%8
    const int tile = bid >> 6;                   // 0..15
    const int lane = tid & 63;
    const int pos  = lane & 15;
    const int quad = lane >> 4;
    const int wv   = __builtin_amdgcn_readfirstlane(tid >> 6);
    const int row0 = tile * 64;
    const int wrow = wv << 4;

    unsigned* flags = (unsigned*)(ws + 12713984);

    // ================= phase 0: convert own slice ==========================
    cvt_slice(n, tile, tid, W1, W2, W3, ws);
    __syncthreads();                              // all 256 threads' stores issued+drained (vmcnt0)

    // ---- node-group sync: release own flag, acquire all 16 ----
    if (tid == 0) {
        __hip_atomic_store(&flags[(n << 4) + tile], MAGICF,
                           __ATOMIC_RELEASE, __HIP_MEMORY_SCOPE_AGENT);
        unsigned miss = 0;
        for (int j = 0; j < 16; ++j) {
            bool ok = false;
            for (int sp = 0; sp < 32768; ++sp) {
                if (__hip_atomic_load(&flags[(n << 4) + j],
                                      __ATOMIC_ACQUIRE, __HIP_MEMORY_SCOPE_AGENT) == MAGICF)
                    { ok = true; break; }
                __builtin_amdgcn_s_sleep(2);
            }
            if (!ok) miss |= 1u << j;
        }
        missLds = miss;
    }
    __syncthreads();
    if (missLds) {                                // self-repair: convert missing slices
        unsigned miss = missLds;                  // (identical values -> race-safe)
        while (miss) {
            const int j = __builtin_ctz(miss);
            miss &= miss - 1;
            cvt_slice(n, j, tid, W1, W2, W3, ws);
        }
        asm volatile("s_waitcnt vmcnt(0)" ::: "memory");
    }
    __syncthreads();                              // repair (if any) visible WG-wide

    // ================= phase 1: MFMA pipeline ==============================
    const _Float16* W1h = (const _Float16*)ws + (size_t)n * 32768;
    const h8*       W2f = (const h8*)(ws + 4194304) + (size_t)n * 4096;
    const _Float16* W3h = (const _Float16*)(ws + 8388608) + (size_t)n * 32768;
    const float*   w3cp = (const float*)(ws + 12582912) + n * 512;

    {   // stage W1 chunk 0
        const _Float16* s1 = W1h + wv * 1024 + lane * 8;
        gld16(s1,       w1b + wv * 1024);
        gld16(s1 + 512, w1b + wv * 1024 + 512);
    }
    #pragma unroll
    for (int k = 0; k < 2; ++k) {
        const int h = tid + k * 256;
        w3cs[h] = w3cp[h];
        b3s[h]  = b3[n * HH + h];
        w4s[h]  = W4[n * HH + h];
    }
    if (tid < 64) xns[tid] = x[(size_t)(row0 + tid) * NN + n];

    // X B-fragments (own element zeroed): lane holds row i = pos
    h8 aX[2];
    #pragma unroll
    for (int ks = 0; ks < 2; ++ks) {
        const float* p = x + (size_t)(row0 + wrow + pos) * NN + ks * 32 + quad * 8;
        float4 a = *(const float4*)p, bq = *(const float4*)(p + 4);
        float v[8] = {a.x, a.y, a.z, a.w, bq.x, bq.y, bq.z, bq.w};
        const int base = ks * 32 + quad * 8;
        #pragma unroll
        for (int j = 0; j < 8; ++j) if (base + j == n) v[j] = 0.f;
        h8 h;
        #pragma unroll
        for (int j = 0; j < 8; ++j) h[j] = (_Float16)v[j];
        aX[ks] = h;
    }
    __syncthreads();                              // tables + chunk-0 staging done

    _Float16* P = priv + wv * 1152;               // own 16x72 buffer
    const float xv = xns[wrow + pos];             // own-column x value (fold term)

    // ---- stages A+B over 8 h-chunks (W1 dbuf staged, W2 reg-loaded) ----
    fx4 acc2[4] = {};
    for (int c = 0; c < 8; ++c) {
        const int cb = c & 1;
        if (c < 7) {                               // stage next W1 chunk
            const _Float16* s1 = W1h + (c + 1) * 4096 + wv * 1024 + lane * 8;
            gld16(s1,       w1b + (cb ^ 1) * 4096 + wv * 1024);
            gld16(s1 + 512, w1b + (cb ^ 1) * 4096 + wv * 1024 + 512);
        } else {                                   // stage W3 chunk 0 into buf 0
            const _Float16* s3 = W3h + wv * 1024 + lane * 8;
            gld16(s3,       w1b + (cb ^ 1) * 4096 + wv * 1024);
            gld16(s3 + 512, w1b + (cb ^ 1) * 4096 + wv * 1024 + 512);
        }
        h8 f2[8];                                  // this chunk's W2 frags
        #pragma unroll
        for (int t = 0; t < 8; ++t) f2[t] = W2f[(c * 8 + t) * 64 + lane];
        // stage A (swapped): h1^T = W1chunk · X^T
        const h8* F1 = (const h8*)(w1b + cb * 4096);
        fx4 accA[4] = {};
        #pragma unroll
        for (int ks = 0; ks < 2; ++ks)
            #pragma unroll
            for (int nt = 0; nt < 4; ++nt)
                accA[nt] = MFMA(F1[(ks * 4 + nt) * 64 + lane], aX[ks], accA[nt], 0, 0, 0);
        // h1^T -> P as h1[i][h] (packed b64), read back as B-frags
        #pragma unroll
        for (int nt = 0; nt < 4; ++nt) {
            h4 w;
            #pragma unroll
            for (int r = 0; r < 4; ++r) w[r] = (_Float16)fmaxf(accA[nt][r], 0.f);
            *(h4*)(P + pos * 72 + nt * 16 + quad * 4) = w;
        }
        h8 aH[2];
        #pragma unroll
        for (int ks = 0; ks < 2; ++ks)
            aH[ks] = *(const h8*)(P + pos * 72 + ks * 32 + quad * 8);
        // stage B (swapped): r1^T += W2chunk · h1^T
        #pragma unroll
        for (int ks = 0; ks < 2; ++ks)
            #pragma unroll
            for (int cm = 0; cm < 4; ++cm)
                acc2[cm] = MFMA(f2[ks * 4 + cm], aH[ks], acc2[cm], 0, 0, 0);
        __syncthreads();                           // staging done + buffer free
    }

    // ---- r1^T -> P (packed b64), read back as B-frags ----
    #pragma unroll
    for (int cm = 0; cm < 4; ++cm) {
        h4 w;
        #pragma unroll
        for (int r = 0; r < 4; ++r) w[r] = (_Float16)fmaxf(acc2[cm][r], 0.f);
        *(h4*)(P + pos * 72 + cm * 16 + quad * 4) = w;
    }
    h8 aR[2];
    #pragma unroll
    for (int ks = 0; ks < 2; ++ks)
        aR[ks] = *(const h8*)(P + pos * 72 + ks * 32 + quad * 8);

    // ---- stage C/D over 8 h-chunks (W3 dbuf staged; fold done in VALU) ----
    float o = 0.f;
    for (int c = 0; c < 8; ++c) {
        const int cb = c & 1;
        const int hc = c << 6;
        if (c < 7) {
            const _Float16* s3 = W3h + (c + 1) * 4096 + wv * 1024 + lane * 8;
            gld16(s3,       w1b + (cb ^ 1) * 4096 + wv * 1024);
            gld16(s3 + 512, w1b + (cb ^ 1) * 4096 + wv * 1024 + 512);
        }
        const h8* F3 = (const h8*)(w1b + cb * 4096);
        fx4 acc3[4] = {};
        #pragma unroll
        for (int ks = 0; ks < 2; ++ks)
            #pragma unroll
            for (int nt = 0; nt < 4; ++nt)
                acc3[nt] = MFMA(F3[(ks * 4 + nt) * 64 + lane], aR[ks], acc3[nt], 0, 0, 0);
        // fold (VALU, fp32): acc3[h][i] += w3c[h]*x[i][n] + b3[h]
        // lane's rows h = hc+nt*16+quad*4+r, col i = pos
        #pragma unroll
        for (int nt = 0; nt < 4; ++nt) {
            const fx4 wc = *(const fx4*)(w3cs + hc + nt * 16 + quad * 4);
            const fx4 bc = *(const fx4*)(b3s  + hc + nt * 16 + quad * 4);
            #pragma unroll
            for (int r = 0; r < 4; ++r)
                acc3[nt][r] = fmaf(wc[r], xv, acc3[nt][r] + bc[r]);
        }
        // stage D: o += relu(h3[h][i]) * W4[h]
        #pragma unroll
        for (int nt = 0; nt < 4; ++nt) {
            const fx4 w4v = *(const fx4*)(w4s + hc + nt * 16 + quad * 4);
            #pragma unroll
            for (int r = 0; r < 4; ++r)
                o = fmaf(fmaxf(acc3[nt][r], 0.f), w4v[r], o);
        }
        __syncthreads();
    }

    // ---- reduce across quads, store ----
    o += __shfl_xor(o, 16, 64);
    o += __shfl_xor(o, 32, 64);
    if (quad == 0) {
        const int row = row0 + wrow + pos;
        out[(size_t)row * 64 + n] = fmaxf(o + b4[n], 0.f);
    }
}

// ---------------------------------------------------------------------------
// Legacy fallback (proven 112 µs kernel) — used only if ws is too small.
// ---------------------------------------------------------------------------
__device__ __forceinline__ void cvt_store16(_Float16* d, const float4* p) {
    h8 h0, h1;
    h0[0]=(_Float16)p[0].x; h0[1]=(_Float16)p[0].y; h0[2]=(_Float16)p[0].z; h0[3]=(_Float16)p[0].w;
    h0[4]=(_Float16)p[1].x; h0[5]=(_Float16)p[1].y; h0[6]=(_Float16)p[1].z; h0[7]=(_Float16)p[1].w;
    h1[0]=(_Float16)p[2].x; h1[1]=(_Float16)p[2].y; h1[2]=(_Float16)p[2].z; h1[3]=(_Float16)p[2].w;
    h1[4]=(_Float16)p[3].x; h1[5]=(_Float16)p[3].y; h1[6]=(_Float16)p[3].z; h1[7]=(_Float16)p[3].w;
    *(h8*)d = h0; *((h8*)d + 1) = h1;
}

__global__ __launch_bounds__(256, 2)
void causal_mfma3(const float* __restrict__ x,  const float* __restrict__ W1,
                  const float* __restrict__ W2, const float* __restrict__ W3,
                  const float* __restrict__ b3, const float* __restrict__ W4,
                  const float* __restrict__ b4, float* __restrict__ out)
{
    __shared__ __align__(16) char smem[61952];
    _Float16* W1c  = (_Float16*)smem;
    _Float16* W2c  = W1c + 2 * 4608;
    _Float16* priv = W2c + 2 * 4608;
    float*    w3cs = (float*)(smem + 55296);
    float*    b3s  = w3cs + 512;
    float*    w4s  = b3s + 512;
    float*    xns  = w4s + 512;

    const int tid  = threadIdx.x;
    const int bid  = blockIdx.x;
    const int n    = bid & 63;
    const int tile = bid >> 6;
    const int lane = tid & 63;
    const int pos  = lane & 15;
    const int quad = lane >> 4;
    const int wv   = __builtin_amdgcn_readfirstlane(tid >> 6);
    const int row0 = tile * 128;
    const int wrow = wv << 5;

    const float* W1n = W1 + (size_t)n * HH * NN;
    const float* W2n = W2 + (size_t)n * NN * HH;
    const float* W3n = W3 + (size_t)n * HH * 128;

    const int trow = tid >> 2;
    const int tcol = (tid & 3) << 4;

    {
        float4 p1[4], p2[4];
        #pragma unroll
        for (int q = 0; q < 4; ++q) p1[q] = *(const float4*)(W1n + trow * 64 + tcol + q * 4);
        #pragma unroll
        for (int q = 0; q < 4; ++q) p2[q] = *(const float4*)(W2n + (size_t)trow * HH + tcol + q * 4);
        #pragma unroll
        for (int k = 0; k < 2; ++k) {
            const int h = tid + k * 256;
            w3cs[h] = W3n[(size_t)h * 128 + 64 + n];
            b3s[h]  = b3[n * HH + h];
            w4s[h]  = W4[n * HH + h];
        }
        if (tid < 128) xns[tid] = x[(size_t)(row0 + tid) * NN + n];
        cvt_store16(W1c + trow * 72 + tcol, p1);
        cvt_store16(W2c + trow * 72 + tcol, p2);
    }

    h8 aX[2][2];
    #pragma unroll
    for (int mt = 0; mt < 2; ++mt)
        #pragma unroll
        for (int ks = 0; ks < 2; ++ks) {
            const float* p = x + (size_t)(row0 + wrow + mt * 16 + pos) * NN + ks * 32 + quad * 8;
            float4 a = *(const float4*)p, bq = *(const float4*)(p + 4);
            float v[8] = {a.x, a.y, a.z, a.w, bq.x, bq.y, bq.z, bq.w};
            const int base = ks * 32 + quad * 8;
            #pragma unroll
            for (int j = 0; j < 8; ++j) if (base + j == n) v[j] = 0.f;
            h8 h;
            #pragma unroll
            for (int j = 0; j < 8; ++j) h[j] = (_Float16)v[j];
            aX[mt][ks] = h;
        }
    __syncthreads();

    _Float16* P = priv + wv * 2304;

    fx4 acc2[2][4] = {};
    for (int c = 0; c < 8; ++c) {
        const int cb = c & 1;
        float4 p1[4], p2[4];
        if (c < 7) {
            const int hb1 = (c + 1) << 6;
            #pragma unroll
            for (int q = 0; q < 4; ++q) p1[q] = *(const float4*)(W1n + (hb1 + trow) * 64 + tcol + q * 4);
            #pragma unroll
            for (int q = 0; q < 4; ++q) p2[q] = *(const float4*)(W2n + (size_t)trow * HH + hb1 + tcol + q * 4);
        }
        const _Float16* W1L = W1c + cb * 4608;
        fx4 accA[2][4] = {};
        #pragma unroll
        for (int ks = 0; ks < 2; ++ks)
            #pragma unroll
            for (int nt = 0; nt < 4; ++nt) {
                h8 bf = *(const h8*)(W1L + (nt * 16 + pos) * 72 + ks * 32 + quad * 8);
                accA[0][nt] = MFMA(aX[0][ks], bf, accA[0][nt], 0, 0, 0);
                accA[1][nt] = MFMA(aX[1][ks], bf, accA[1][nt], 0, 0, 0);
            }
        #pragma unroll
        for (int mt = 0; mt < 2; ++mt)
            #pragma unroll
            for (int nt = 0; nt < 4; ++nt)
                #pragma unroll
                for (int r = 0; r < 4; ++r)
                    P[(mt * 16 + quad * 4 + r) * 72 + nt * 16 + pos] =
                        (_Float16)fmaxf(accA[mt][nt][r], 0.f);
        h8 aH[2][2];
        #pragma unroll
        for (int mt = 0; mt < 2; ++mt)
            #pragma unroll
            for (int ks = 0; ks < 2; ++ks)
                aH[mt][ks] = *(const h8*)(P + (mt * 16 + pos) * 72 + ks * 32 + quad * 8);
        const _Float16* W2L = W2c + cb * 4608;
        #pragma unroll
        for (int ks = 0; ks < 2; ++ks)
            #pragma unroll
            for (int cm = 0; cm < 4; ++cm) {
                h8 bf = *(const h8*)(W2L + (cm * 16 + pos) * 72 + ks * 32 + quad * 8);
                acc2[0][cm] = MFMA(aH[0][ks], bf, acc2[0][cm], 0, 0, 0);
                acc2[1][cm] = MFMA(aH[1][ks], bf, acc2[1][cm], 0, 0, 0);
            }
        if (c < 7) {
            cvt_store16(W1c + (cb ^ 1) * 4608 + trow * 72 + tcol, p1);
            cvt_store16(W2c + (cb ^ 1) * 4608 + trow * 72 + tcol, p2);
        }
        __syncthreads();
    }

    #pragma unroll
    for (int mt = 0; mt < 2; ++mt)
        #pragma unroll
        for (int cm = 0; cm < 4; ++cm)
            #pragma unroll
            for (int r = 0; r < 4; ++r)
                P[(mt * 16 + quad * 4 + r) * 72 + cm * 16 + pos] =
                    (_Float16)fmaxf(acc2[mt][cm][r], 0.f);
    h8 aR[2][2];
    #pragma unroll
    for (int mt = 0; mt < 2; ++mt)
        #pragma unroll
        for (int ks = 0; ks < 2; ++ks)
            aR[mt][ks] = *(const h8*)(P + (mt * 16 + pos) * 72 + ks * 32 + quad * 8);
    h8 af3[2];
    #pragma unroll
    for (int mt = 0; mt < 2; ++mt) {
        h8 h;
        #pragma unroll
        for (int j = 0; j < 8; ++j) h[j] = (_Float16)0.f;
        if (quad == 0) { h[0] = (_Float16)xns[wrow + mt * 16 + pos]; h[1] = (_Float16)1.f; }
        af3[mt] = h;
    }

    {
        float4 p3[4];
        #pragma unroll
        for (int q = 0; q < 4; ++q) p3[q] = *(const float4*)(W3n + (size_t)trow * 128 + tcol + q * 4);
        cvt_store16(W1c + trow * 72 + tcol, p3);
    }
    __syncthreads();

    float o[2][4] = {};
    for (int c = 0; c < 8; ++c) {
        const int cb = c & 1;
        const int hc = c << 6;
        float4 p3[4];
        if (c < 7) {
            #pragma unroll
            for (int q = 0; q < 4; ++q)
                p3[q] = *(const float4*)(W3n + (size_t)(hc + 64 + trow) * 128 + tcol + q * 4);
        }
        const _Float16* W3L = W1c + cb * 4608;
        fx4 acc3[2][4] = {};
        #pragma unroll
        for (int ks = 0; ks < 2; ++ks)
            #pragma unroll
            for (int nt = 0; nt < 4; ++nt) {
                h8 bf = *(const h8*)(W3L + (nt * 16 + pos) * 72 + ks * 32 + quad * 8);
                acc3[0][nt] = MFMA(aR[0][ks], bf, acc3[0][nt], 0, 0, 0);
                acc3[1][nt] = MFMA(aR[1][ks], bf, acc3[1][nt], 0, 0, 0);
            }
        #pragma unroll
        for (int nt = 0; nt < 4; ++nt) {
            h8 bf3;
            #pragma unroll
            for (int j = 0; j < 8; ++j) bf3[j] = (_Float16)0.f;
            if (quad == 0) {
                const int h = hc + nt * 16 + pos;
                bf3[0] = (_Float16)w3cs[h];
                bf3[1] = (_Float16)b3s[h];
            }
            acc3[0][nt] = MFMA(af3[0], bf3, acc3[0][nt], 0, 0, 0);
            acc3[1][nt] = MFMA(af3[1], bf3, acc3[1][nt], 0, 0, 0);
        }
        #pragma unroll
        for (int nt = 0; nt < 4; ++nt) {
            const float w4v = w4s[hc + nt * 16 + pos];
            #pragma unroll
            for (int mt = 0; mt < 2; ++mt)
                #pragma unroll
                for (int r = 0; r < 4; ++r)
                    o[mt][r] = fmaf(fmaxf(acc3[mt][nt][r], 0.f), w4v, o[mt][r]);
        }
        if (c < 7) cvt_store16(W1c + (cb ^ 1) * 4608 + trow * 72 + tcol, p3);
        __syncthreads();
    }

    #pragma unroll
    for (int m = 1; m < 16; m <<= 1)
        #pragma unroll
        for (int mt = 0; mt < 2; ++mt)
            #pragma unroll
            for (int r = 0; r < 4; ++r)
                o[mt][r] += __shfl_xor(o[mt][r], m, 64);

    if (pos == 0) {
        const float bb = b4[n];
        #pragma unroll
        for (int mt = 0; mt < 2; ++mt)
            #pragma unroll
            for (int r = 0; r < 4; ++r) {
                const int row = row0 + wrow + mt * 16 + quad * 4 + r;
                out[(size_t)row * 64 + n] = fmaxf(o[mt][r] + bb, 0.f);
            }
    }
}

extern "C" void kernel_launch(void* const* d_in, const int* in_sizes, int n_in,
                              void* d_out, int out_size, void* d_ws, size_t ws_size,
                              hipStream_t stream)
{
    const float* x  = (const float*)d_in[0];
    const float* W1 = (const float*)d_in[1];
    const float* W2 = (const float*)d_in[2];
    const float* W3 = (const float*)d_in[3];
    const float* b3 = (const float*)d_in[4];
    const float* W4 = (const float*)d_in[5];
    const float* b4 = (const float*)d_in[6];
    float* out = (float*)d_out;

    if (d_ws != nullptr && ws_size >= WS_NEEDED) {
        hipLaunchKernelGGL(causal_fused2, dim3(1024), dim3(256), 0, stream,
                           x, W1, W2, W3, b3, W4, b4, (char*)d_ws, out);
    } else {
        hipLaunchKernelGGL(causal_mfma3, dim3(512), dim3(256), 0, stream,
                           x, W1, W2, W3, b3, W4, b4, out);
    }
}

// Round 8
// 110.666 us; speedup vs baseline: 2.2363x; 2.2363x over previous
//
#include <hip/hip_runtime.h>

#define NN 64
#define HH 512

typedef _Float16 h8 __attribute__((ext_vector_type(8)));
typedef _Float16 h4 __attribute__((ext_vector_type(4)));
typedef float    fx4 __attribute__((ext_vector_type(4)));

#define MFMA __builtin_amdgcn_mfma_f32_16x16x32_f16

// ---------------------------------------------------------------------------
// ws layout (bytes):
//   [0,        4 MiB)  W1f : per node, frag-ordered fp16 [8 c][2 ks][4 nt][64 lane][8]
//   [4 MiB,    8 MiB)  W2f : same shape
//   [8 MiB,   12 MiB)  W3f : same shape (cols 0..63 of W3)
//   [12 MiB, +128 KiB) w3c : per node, [512] fp32 = W3n[h][64+n]
// total = 12,713,984 B
// For mfma_f32_16x16x32_f16 the A-frag and B-frag lane layouts are identical,
// so the same frag data serves swapped-operand MFMAs unchanged.
// ---------------------------------------------------------------------------
#define WS_NEEDED 12713984ull

typedef __attribute__((address_space(1))) const unsigned int gu32;
typedef __attribute__((address_space(3))) unsigned int       lu32;

__device__ __forceinline__ void gld16(const void* g, void* l) {
    // DMA 16B/lane global->LDS; LDS dest = wave-uniform base + lane*16
    __builtin_amdgcn_global_load_lds((gu32*)g, (lu32*)l, 16, 0, 0);
}

__device__ __forceinline__ h8 cvt8(const float* __restrict__ s) {
    float4 a = *(const float4*)s, b = *(const float4*)(s + 4);
    h8 h;
    h[0]=(_Float16)a.x; h[1]=(_Float16)a.y; h[2]=(_Float16)a.z; h[3]=(_Float16)a.w;
    h[4]=(_Float16)b.x; h[5]=(_Float16)b.y; h[6]=(_Float16)b.z; h[7]=(_Float16)b.w;
    return h;
}

// One thread per 16B frag block in each of W1f/W2f/W3f.
// g decodes as [n:6][c:3][ks:1][nt:2][lane:6]; node n's work runs on blocks
// with bid%8 == n%8 (home XCD) so dirty L2 lines land where consumers read.
__global__ __launch_bounds__(256)
void cvt_frag(const float* __restrict__ W1, const float* __restrict__ W2,
              const float* __restrict__ W3, char* __restrict__ ws)
{
    const int bid  = blockIdx.x;                 // 0..1023
    const int nb   = bid & 63;
    const int sub  = bid >> 6;                   // 0..15
    const int g    = nb * 4096 + sub * 256 + threadIdx.x;
    const int n    = g >> 12;                    // == nb
    const int c    = (g >> 9) & 7;
    const int ks   = (g >> 8) & 1;
    const int nt   = (g >> 6) & 3;
    const int l    = g & 63;
    const int pos  = l & 15;
    const int quad = l >> 4;

    _Float16* o1 = (_Float16*)ws;
    _Float16* o2 = o1 + 2097152;
    _Float16* o3 = o2 + 2097152;
    float*    oc = (float*)(ws + 12582912);

    {   // W1 frag: W1[n][c*64 + nt*16 + pos][ks*32 + quad*8 + j]
        const float* s = W1 + (size_t)n * 32768
                            + (size_t)(c * 64 + nt * 16 + pos) * 64
                            + ks * 32 + quad * 8;
        *(h8*)(o1 + (size_t)g * 8) = cvt8(s);
    }
    {   // W2 frag: W2[n][nt*16 + pos][c*64 + ks*32 + quad*8 + j]
        const float* s = W2 + (size_t)n * 32768
                            + (size_t)(nt * 16 + pos) * 512
                            + c * 64 + ks * 32 + quad * 8;
        *(h8*)(o2 + (size_t)g * 8) = cvt8(s);
    }
    {   // W3 frag (cols < 64): W3[n][c*64 + nt*16 + pos][ks*32 + quad*8 + j]
        const float* s = W3 + (size_t)n * 65536
                            + (size_t)(c * 64 + nt * 16 + pos) * 128
                            + ks * 32 + quad * 8;
        *(h8*)(o3 + (size_t)g * 8) = cvt8(s);
    }
    if (g < 32768) {  // w3c gather: oc[n][h] = W3[n][h][64+n]
        const int n3 = g >> 9;
        const int h3 = g & 511;
        oc[g] = W3[(size_t)n3 * 65536 + (size_t)h3 * 128 + 64 + n3];
    }
}

// ---------------------------------------------------------------------------
// Main kernel (mfma9 = mfma8 with the LDS-overlap bug fixed):
// 1024 WGs x 256 thr, 4 blocks/CU. WG = (node n = bid&63, tile of 64 rows);
// wave owns 16 rows. Phase A+B: W1 staged gld_lds dbuf (7 barriers),
// W2 frags reg-loaded. Stage C/D: W3 frags reg-prefetched depth-1 (named
// dbuf, static indices) -> ZERO barriers. Swapped-operand MFMAs with packed
// ds_write_b64 transposes; fold done in fp32 VALU.
// LDS map (32000 B): w1b [0,16384) | priv [16384,25600) | w3cs [25600,27648)
//                    | b3s [27648,29696) | w4s [29696,31744) | xns [31744,32000)
// ---------------------------------------------------------------------------
__global__ __launch_bounds__(256, 4)
void causal_mfma9(const float* __restrict__ x, const char* __restrict__ ws,
                  const float* __restrict__ b3, const float* __restrict__ W4,
                  const float* __restrict__ b4, float* __restrict__ out)
{
    __shared__ __align__(16) char smem[32000];
    _Float16* w1b  = (_Float16*)smem;            // [2][4096] halves (W1 dbuf)
    _Float16* priv = w1b + 8192;                 // [4 waves][16][72] halves (9216 B)
    float*    w3cs = (float*)(smem + 25600);     // [512] fp32
    float*    b3s  = (float*)(smem + 27648);     // [512] fp32
    float*    w4s  = (float*)(smem + 29696);     // [512] fp32
    float*    xns  = (float*)(smem + 31744);     // [64]  fp32

    const int tid  = threadIdx.x;
    const int bid  = blockIdx.x;
    const int n    = bid & 63;                   // same-node WGs on XCD n%8
    const int tile = bid >> 6;                   // 0..15
    const int lane = tid & 63;
    const int pos  = lane & 15;
    const int quad = lane >> 4;
    const int wv   = __builtin_amdgcn_readfirstlane(tid >> 6);
    const int row0 = tile * 64;
    const int wrow = wv << 4;                    // wave's 16-row base

    const _Float16* W1h = (const _Float16*)ws + (size_t)n * 32768;
    const h8*       W2f = (const h8*)(ws + 4194304) + (size_t)n * 4096;
    const h8*       W3f = (const h8*)(ws + 8388608) + (size_t)n * 4096;
    const float*   w3cp = (const float*)(ws + 12582912) + n * 512;

    // ---- prologue: stage W1 chunk 0, scalar tables, xn, aX frags ----
    {
        const _Float16* s1 = W1h + wv * 1024 + lane * 8;
        gld16(s1,       w1b + wv * 1024);
        gld16(s1 + 512, w1b + wv * 1024 + 512);
    }
    #pragma unroll
    for (int k = 0; k < 2; ++k) {
        const int h = tid + k * 256;
        w3cs[h] = w3cp[h];
        b3s[h]  = b3[n * HH + h];
        w4s[h]  = W4[n * HH + h];
    }
    if (tid < 64) xns[tid] = x[(size_t)(row0 + tid) * NN + n];

    // X B-fragments (own element zeroed): lane holds row i = pos
    h8 aX[2];
    #pragma unroll
    for (int ks = 0; ks < 2; ++ks) {
        const float* p = x + (size_t)(row0 + wrow + pos) * NN + ks * 32 + quad * 8;
        float4 a = *(const float4*)p, bq = *(const float4*)(p + 4);
        float v[8] = {a.x, a.y, a.z, a.w, bq.x, bq.y, bq.z, bq.w};
        const int base = ks * 32 + quad * 8;
        #pragma unroll
        for (int j = 0; j < 8; ++j) if (base + j == n) v[j] = 0.f;
        h8 h;
        #pragma unroll
        for (int j = 0; j < 8; ++j) h[j] = (_Float16)v[j];
        aX[ks] = h;
    }
    __syncthreads();                              // tables + chunk-0 staging done

    _Float16* P = priv + wv * 1152;               // own 16x72 buffer
    const float xv = xns[wrow + pos];             // own-column x value (fold term)

    // ---- stages A+B over 8 h-chunks (W1 dbuf staged, W2 reg-loaded) ----
    fx4 acc2[4] = {};
    for (int c = 0; c < 8; ++c) {
        const int cb = c & 1;
        if (c < 7) {                               // stage next W1 chunk
            const _Float16* s1 = W1h + (c + 1) * 4096 + wv * 1024 + lane * 8;
            gld16(s1,       w1b + (cb ^ 1) * 4096 + wv * 1024);
            gld16(s1 + 512, w1b + (cb ^ 1) * 4096 + wv * 1024 + 512);
        }
        h8 f2[8];                                  // this chunk's W2 frags
        #pragma unroll
        for (int t = 0; t < 8; ++t) f2[t] = W2f[(c * 8 + t) * 64 + lane];
        // stage A (swapped): h1^T = W1chunk · X^T
        const h8* F1 = (const h8*)(w1b + cb * 4096);
        fx4 accA[4] = {};
        #pragma unroll
        for (int ks = 0; ks < 2; ++ks)
            #pragma unroll
            for (int nt = 0; nt < 4; ++nt)
                accA[nt] = MFMA(F1[(ks * 4 + nt) * 64 + lane], aX[ks], accA[nt], 0, 0, 0);
        // h1^T -> P as h1[i][h] (packed b64), read back as B-frags
        #pragma unroll
        for (int nt = 0; nt < 4; ++nt) {
            h4 w;
            #pragma unroll
            for (int r = 0; r < 4; ++r) w[r] = (_Float16)fmaxf(accA[nt][r], 0.f);
            *(h4*)(P + pos * 72 + nt * 16 + quad * 4) = w;
        }
        h8 aH[2];
        #pragma unroll
        for (int ks = 0; ks < 2; ++ks)
            aH[ks] = *(const h8*)(P + pos * 72 + ks * 32 + quad * 8);
        // stage B (swapped): r1^T += W2chunk · h1^T
        #pragma unroll
        for (int ks = 0; ks < 2; ++ks)
            #pragma unroll
            for (int cm = 0; cm < 4; ++cm)
                acc2[cm] = MFMA(f2[ks * 4 + cm], aH[ks], acc2[cm], 0, 0, 0);
        if (c < 7) __syncthreads();                // dbuf staging complete
    }

    // ---- r1^T -> P (packed b64), read back as B-frags ----
    #pragma unroll
    for (int cm = 0; cm < 4; ++cm) {
        h4 w;
        #pragma unroll
        for (int r = 0; r < 4; ++r) w[r] = (_Float16)fmaxf(acc2[cm][r], 0.f);
        *(h4*)(P + pos * 72 + cm * 16 + quad * 4) = w;
    }
    h8 aR[2];
    #pragma unroll
    for (int ks = 0; ks < 2; ++ks)
        aR[ks] = *(const h8*)(P + pos * 72 + ks * 32 + quad * 8);

    // ---- stage C/D over 8 h-chunks (W3 reg-prefetched, ZERO barriers) ----
    float o = 0.f;
    h8 f3a[8], f3b[8];
    #pragma unroll
    for (int t = 0; t < 8; ++t) f3a[t] = W3f[t * 64 + lane];   // chunk 0

    auto bodyC = [&](h8 (&cur3)[8], h8 (&nxt3)[8], int c) {
        const int hc = c << 6;
        if (c < 7) {                               // depth-1 prefetch (static regs)
            #pragma unroll
            for (int t = 0; t < 8; ++t) nxt3[t] = W3f[((c + 1) * 8 + t) * 64 + lane];
        }
        fx4 acc3[4] = {};
        #pragma unroll
        for (int ks = 0; ks < 2; ++ks)
            #pragma unroll
            for (int nt = 0; nt < 4; ++nt)
                acc3[nt] = MFMA(cur3[ks * 4 + nt], aR[ks], acc3[nt], 0, 0, 0);
        // fold (VALU, fp32): acc3[h][i] += w3c[h]*x[i][n] + b3[h]
        #pragma unroll
        for (int nt = 0; nt < 4; ++nt) {
            const fx4 wc = *(const fx4*)(w3cs + hc + nt * 16 + quad * 4);
            const fx4 bc = *(const fx4*)(b3s  + hc + nt * 16 + quad * 4);
            #pragma unroll
            for (int r = 0; r < 4; ++r)
                acc3[nt][r] = fmaf(wc[r], xv, acc3[nt][r] + bc[r]);
        }
        // stage D: o += relu(h3[h][i]) * W4[h]
        #pragma unroll
        for (int nt = 0; nt < 4; ++nt) {
            const fx4 w4v = *(const fx4*)(w4s + hc + nt * 16 + quad * 4);
            #pragma unroll
            for (int r = 0; r < 4; ++r)
                o = fmaf(fmaxf(acc3[nt][r], 0.f), w4v[r], o);
        }
    };
    for (int c = 0; c < 8; c += 2) { bodyC(f3a, f3b, c); bodyC(f3b, f3a, c + 1); }

    // ---- reduce across quads, store ----
    o += __shfl_xor(o, 16, 64);
    o += __shfl_xor(o, 32, 64);
    if (quad == 0) {
        const int row = row0 + wrow + pos;
        out[(size_t)row * 64 + n] = fmaxf(o + b4[n], 0.f);
    }
}

// ---------------------------------------------------------------------------
// Legacy fallback (proven 112 µs kernel) — used only if ws is too small.
// ---------------------------------------------------------------------------
__device__ __forceinline__ void cvt_store16(_Float16* d, const float4* p) {
    h8 h0, h1;
    h0[0]=(_Float16)p[0].x; h0[1]=(_Float16)p[0].y; h0[2]=(_Float16)p[0].z; h0[3]=(_Float16)p[0].w;
    h0[4]=(_Float16)p[1].x; h0[5]=(_Float16)p[1].y; h0[6]=(_Float16)p[1].z; h0[7]=(_Float16)p[1].w;
    h1[0]=(_Float16)p[2].x; h1[1]=(_Float16)p[2].y; h1[2]=(_Float16)p[2].z; h1[3]=(_Float16)p[2].w;
    h1[4]=(_Float16)p[3].x; h1[5]=(_Float16)p[3].y; h1[6]=(_Float16)p[3].z; h1[7]=(_Float16)p[3].w;
    *(h8*)d = h0; *((h8*)d + 1) = h1;
}

__global__ __launch_bounds__(256, 2)
void causal_mfma3(const float* __restrict__ x,  const float* __restrict__ W1,
                  const float* __restrict__ W2, const float* __restrict__ W3,
                  const float* __restrict__ b3, const float* __restrict__ W4,
                  const float* __restrict__ b4, float* __restrict__ out)
{
    __shared__ __align__(16) char smem[61952];
    _Float16* W1c  = (_Float16*)smem;
    _Float16* W2c  = W1c + 2 * 4608;
    _Float16* priv = W2c + 2 * 4608;
    float*    w3cs = (float*)(smem + 55296);
    float*    b3s  = w3cs + 512;
    float*    w4s  = b3s + 512;
    float*    xns  = w4s + 512;

    const int tid  = threadIdx.x;
    const int bid  = blockIdx.x;
    const int n    = bid & 63;
    const int tile = bid >> 6;
    const int lane = tid & 63;
    const int pos  = lane & 15;
    const int quad = lane >> 4;
    const int wv   = __builtin_amdgcn_readfirstlane(tid >> 6);
    const int row0 = tile * 128;
    const int wrow = wv << 5;

    const float* W1n = W1 + (size_t)n * HH * NN;
    const float* W2n = W2 + (size_t)n * NN * HH;
    const float* W3n = W3 + (size_t)n * HH * 128;

    const int trow = tid >> 2;
    const int tcol = (tid & 3) << 4;

    {
        float4 p1[4], p2[4];
        #pragma unroll
        for (int q = 0; q < 4; ++q) p1[q] = *(const float4*)(W1n + trow * 64 + tcol + q * 4);
        #pragma unroll
        for (int q = 0; q < 4; ++q) p2[q] = *(const float4*)(W2n + (size_t)trow * HH + tcol + q * 4);
        #pragma unroll
        for (int k = 0; k < 2; ++k) {
            const int h = tid + k * 256;
            w3cs[h] = W3n[(size_t)h * 128 + 64 + n];
            b3s[h]  = b3[n * HH + h];
            w4s[h]  = W4[n * HH + h];
        }
        if (tid < 128) xns[tid] = x[(size_t)(row0 + tid) * NN + n];
        cvt_store16(W1c + trow * 72 + tcol, p1);
        cvt_store16(W2c + trow * 72 + tcol, p2);
    }

    h8 aX[2][2];
    #pragma unroll
    for (int mt = 0; mt < 2; ++mt)
        #pragma unroll
        for (int ks = 0; ks < 2; ++ks) {
            const float* p = x + (size_t)(row0 + wrow + mt * 16 + pos) * NN + ks * 32 + quad * 8;
            float4 a = *(const float4*)p, bq = *(const float4*)(p + 4);
            float v[8] = {a.x, a.y, a.z, a.w, bq.x, bq.y, bq.z, bq.w};
            const int base = ks * 32 + quad * 8;
            #pragma unroll
            for (int j = 0; j < 8; ++j) if (base + j == n) v[j] = 0.f;
            h8 h;
            #pragma unroll
            for (int j = 0; j < 8; ++j) h[j] = (_Float16)v[j];
            aX[mt][ks] = h;
        }
    __syncthreads();

    _Float16* P = priv + wv * 2304;

    fx4 acc2[2][4] = {};
    for (int c = 0; c < 8; ++c) {
        const int cb = c & 1;
        float4 p1[4], p2[4];
        if (c < 7) {
            const int hb1 = (c + 1) << 6;
            #pragma unroll
            for (int q = 0; q < 4; ++q) p1[q] = *(const float4*)(W1n + (hb1 + trow) * 64 + tcol + q * 4);
            #pragma unroll
            for (int q = 0; q < 4; ++q) p2[q] = *(const float4*)(W2n + (size_t)trow * HH + hb1 + tcol + q * 4);
        }
        const _Float16* W1L = W1c + cb * 4608;
        fx4 accA[2][4] = {};
        #pragma unroll
        for (int ks = 0; ks < 2; ++ks)
            #pragma unroll
            for (int nt = 0; nt < 4; ++nt) {
                h8 bf = *(const h8*)(W1L + (nt * 16 + pos) * 72 + ks * 32 + quad * 8);
                accA[0][nt] = MFMA(aX[0][ks], bf, accA[0][nt], 0, 0, 0);
                accA[1][nt] = MFMA(aX[1][ks], bf, accA[1][nt], 0, 0, 0);
            }
        #pragma unroll
        for (int mt = 0; mt < 2; ++mt)
            #pragma unroll
            for (int nt = 0; nt < 4; ++nt)
                #pragma unroll
                for (int r = 0; r < 4; ++r)
                    P[(mt * 16 + quad * 4 + r) * 72 + nt * 16 + pos] =
                        (_Float16)fmaxf(accA[mt][nt][r], 0.f);
        h8 aH[2][2];
        #pragma unroll
        for (int mt = 0; mt < 2; ++mt)
            #pragma unroll
            for (int ks = 0; ks < 2; ++ks)
                aH[mt][ks] = *(const h8*)(P + (mt * 16 + pos) * 72 + ks * 32 + quad * 8);
        const _Float16* W2L = W2c + cb * 4608;
        #pragma unroll
        for (int ks = 0; ks < 2; ++ks)
            #pragma unroll
            for (int cm = 0; cm < 4; ++cm) {
                h8 bf = *(const h8*)(W2L + (cm * 16 + pos) * 72 + ks * 32 + quad * 8);
                acc2[0][cm] = MFMA(aH[0][ks], bf, acc2[0][cm], 0, 0, 0);
                acc2[1][cm] = MFMA(aH[1][ks], bf, acc2[1][cm], 0, 0, 0);
            }
        if (c < 7) {
            cvt_store16(W1c + (cb ^ 1) * 4608 + trow * 72 + tcol, p1);
            cvt_store16(W2c + (cb ^ 1) * 4608 + trow * 72 + tcol, p2);
        }
        __syncthreads();
    }

    #pragma unroll
    for (int mt = 0; mt < 2; ++mt)
        #pragma unroll
        for (int cm = 0; cm < 4; ++cm)
            #pragma unroll
            for (int r = 0; r < 4; ++r)
                P[(mt * 16 + quad * 4 + r) * 72 + cm * 16 + pos] =
                    (_Float16)fmaxf(acc2[mt][cm][r], 0.f);
    h8 aR[2][2];
    #pragma unroll
    for (int mt = 0; mt < 2; ++mt)
        #pragma unroll
        for (int ks = 0; ks < 2; ++ks)
            aR[mt][ks] = *(const h8*)(P + (mt * 16 + pos) * 72 + ks * 32 + quad * 8);
    h8 af3[2];
    #pragma unroll
    for (int mt = 0; mt < 2; ++mt) {
        h8 h;
        #pragma unroll
        for (int j = 0; j < 8; ++j) h[j] = (_Float16)0.f;
        if (quad == 0) { h[0] = (_Float16)xns[wrow + mt * 16 + pos]; h[1] = (_Float16)1.f; }
        af3[mt] = h;
    }

    {
        float4 p3[4];
        #pragma unroll
        for (int q = 0; q < 4; ++q) p3[q] = *(const float4*)(W3n + (size_t)trow * 128 + tcol + q * 4);
        cvt_store16(W1c + trow * 72 + tcol, p3);
    }
    __syncthreads();

    float o[2][4] = {};
    for (int c = 0; c < 8; ++c) {
        const int cb = c & 1;
        const int hc = c << 6;
        float4 p3[4];
        if (c < 7) {
            #pragma unroll
            for (int q = 0; q < 4; ++q)
                p3[q] = *(const float4*)(W3n + (size_t)(hc + 64 + trow) * 128 + tcol + q * 4);
        }
        const _Float16* W3L = W1c + cb * 4608;
        fx4 acc3[2][4] = {};
        #pragma unroll
        for (int ks = 0; ks < 2; ++ks)
            #pragma unroll
            for (int nt = 0; nt < 4; ++nt) {
                h8 bf = *(const h8*)(W3L + (nt * 16 + pos) * 72 + ks * 32 + quad * 8);
                acc3[0][nt] = MFMA(aR[0][ks], bf, acc3[0][nt], 0, 0, 0);
                acc3[1][nt] = MFMA(aR[1][ks], bf, acc3[1][nt], 0, 0, 0);
            }
        #pragma unroll
        for (int nt = 0; nt < 4; ++nt) {
            h8 bf3;
            #pragma unroll
            for (int j = 0; j < 8; ++j) bf3[j] = (_Float16)0.f;
            if (quad == 0) {
                const int h = hc + nt * 16 + pos;
                bf3[0] = (_Float16)w3cs[h];
                bf3[1] = (_Float16)b3s[h];
            }
            acc3[0][nt] = MFMA(af3[0], bf3, acc3[0][nt], 0, 0, 0);
            acc3[1][nt] = MFMA(af3[1], bf3, acc3[1][nt], 0, 0, 0);
        }
        #pragma unroll
        for (int nt = 0; nt < 4; ++nt) {
            const float w4v = w4s[hc + nt * 16 + pos];
            #pragma unroll
            for (int mt = 0; mt < 2; ++mt)
                #pragma unroll
                for (int r = 0; r < 4; ++r)
                    o[mt][r] = fmaf(fmaxf(acc3[mt][nt][r], 0.f), w4v, o[mt][r]);
        }
        if (c < 7) cvt_store16(W1c + (cb ^ 1) * 4608 + trow * 72 + tcol, p3);
        __syncthreads();
    }

    #pragma unroll
    for (int m = 1; m < 16; m <<= 1)
        #pragma unroll
        for (int mt = 0; mt < 2; ++mt)
            #pragma unroll
            for (int r = 0; r < 4; ++r)
                o[mt][r] += __shfl_xor(o[mt][r], m, 64);

    if (pos == 0) {
        const float bb = b4[n];
        #pragma unroll
        for (int mt = 0; mt < 2; ++mt)
            #pragma unroll
            for (int r = 0; r < 4; ++r) {
                const int row = row0 + wrow + mt * 16 + quad * 4 + r;
                out[(size_t)row * 64 + n] = fmaxf(o[mt][r] + bb, 0.f);
            }
    }
}

extern "C" void kernel_launch(void* const* d_in, const int* in_sizes, int n_in,
                              void* d_out, int out_size, void* d_ws, size_t ws_size,
                              hipStream_t stream)
{
    const float* x  = (const float*)d_in[0];
    const float* W1 = (const float*)d_in[1];
    const float* W2 = (const float*)d_in[2];
    const float* W3 = (const float*)d_in[3];
    const float* b3 = (const float*)d_in[4];
    const float* W4 = (const float*)d_in[5];
    const float* b4 = (const float*)d_in[6];
    float* out = (float*)d_out;

    if (d_ws != nullptr && ws_size >= WS_NEEDED) {
        hipLaunchKernelGGL(cvt_frag, dim3(1024), dim3(256), 0, stream,
                           W1, W2, W3, (char*)d_ws);
        hipLaunchKernelGGL(causal_mfma9, dim3(1024), dim3(256), 0, stream,
                           x, (const char*)d_ws, b3, W4, b4, out);
    } else {
        hipLaunchKernelGGL(causal_mfma3, dim3(512), dim3(256), 0, stream,
                           x, W1, W2, W3, b3, W4, b4, out);
    }
}